// Round 1
// baseline (96.269 us; speedup 1.0000x reference)
//
#include <hip/hip_runtime.h>

// Segmented mean over sorted segment ids.
// values: [E, 64] f32, seg_ids: [E] i32 (sorted, in [0,N)), out: [N, 64] f32.
// One wave (64 threads) per segment:
//   - binary search start = lower_bound(s), end = lower_bound(s+1)  (wave-uniform)
//   - lane t accumulates float4 at column (t&15)*4 of rows start+(t>>4), start+(t>>4)+4, ...
//   - shfl_xor(16|32) reduction folds the 4 row-subgroups; lanes 0..15 store float4.
__global__ __launch_bounds__(64) void seg_mean_kernel(
    const float* __restrict__ values,
    const int*   __restrict__ seg_ids,
    float*       __restrict__ out,
    int E, int N)
{
    const int s = blockIdx.x;
    if (s >= N) return;

    // lower_bound(seg_ids, E, s)
    int lo = 0, hi = E;
    while (lo < hi) {
        int mid = (lo + hi) >> 1;
        if (seg_ids[mid] < s) lo = mid + 1; else hi = mid;
    }
    const int start = lo;
    // lower_bound(seg_ids, E, s+1), range [start, E)
    hi = E;
    while (lo < hi) {
        int mid = (lo + hi) >> 1;
        if (seg_ids[mid] <= s) lo = mid + 1; else hi = mid;
    }
    const int end   = lo;
    const int count = end - start;

    const int t    = threadIdx.x;
    const int rsub = t >> 4;          // row-in-group-of-4: 0..3
    const int c4   = (t & 15) << 2;   // column base: 0,4,...,60

    float4 acc = make_float4(0.f, 0.f, 0.f, 0.f);
    for (int r = start + rsub; r < end; r += 4) {
        const float4 v = *reinterpret_cast<const float4*>(values + (size_t)r * 64 + c4);
        acc.x += v.x; acc.y += v.y; acc.z += v.z; acc.w += v.w;
    }

    // fold the 4 row-subgroups (lanes differing in bits 4,5 share the same columns)
    acc.x += __shfl_xor(acc.x, 16, 64);
    acc.y += __shfl_xor(acc.y, 16, 64);
    acc.z += __shfl_xor(acc.z, 16, 64);
    acc.w += __shfl_xor(acc.w, 16, 64);
    acc.x += __shfl_xor(acc.x, 32, 64);
    acc.y += __shfl_xor(acc.y, 32, 64);
    acc.z += __shfl_xor(acc.z, 32, 64);
    acc.w += __shfl_xor(acc.w, 32, 64);

    if (t < 16) {
        const float inv = (count > 0) ? (1.0f / (float)count) : 0.0f;
        float4 o;
        o.x = acc.x * inv; o.y = acc.y * inv; o.z = acc.z * inv; o.w = acc.w * inv;
        *reinterpret_cast<float4*>(out + (size_t)s * 64 + c4) = o;
    }
}

extern "C" void kernel_launch(void* const* d_in, const int* in_sizes, int n_in,
                              void* d_out, int out_size, void* d_ws, size_t ws_size,
                              hipStream_t stream) {
    const float* values  = (const float*)d_in[0];
    const int*   seg_ids = (const int*)d_in[1];
    float*       out     = (float*)d_out;

    const int E = in_sizes[1];        // number of rows (= len(segment_ids))
    const int N = out_size / 64;      // number of segments (D = 64)

    seg_mean_kernel<<<dim3(N), dim3(64), 0, stream>>>(values, seg_ids, out, E, N);
}

// Round 2
// 70.997 us; speedup vs baseline: 1.3560x; 1.3560x over previous
//
#include <hip/hip_runtime.h>

// Segmented mean over sorted segment ids, two-kernel plan:
//   K1 (boundary pre-pass): offs[s] = lower_bound(seg_ids, s) for s in [0, N],
//       computed in O(E) with no searches (ids are sorted).
//   K2 (stream): one wave per segment; lane t accumulates float4 at column
//       (t&15)*4 of rows start+(t>>4), start+(t>>4)+4, ...; shfl_xor fold;
//       lanes 0..15 store. 4 segments (4 waves) per 256-thread block.

__global__ __launch_bounds__(256) void seg_bounds_kernel(
    const int* __restrict__ seg_ids,
    int*       __restrict__ offs,   // [N+1]
    int E, int N)
{
    const int i = blockIdx.x * blockDim.x + threadIdx.x;
    if (i >= E) return;

    const int cur  = seg_ids[i];
    const int prev = (i > 0) ? seg_ids[i - 1] : -1;

    // first row of every segment in (prev, cur] is i (empty segments get the
    // same start as the next non-empty one -> count 0)
    for (int s = prev + 1; s <= cur; ++s) offs[s] = i;

    if (i == E - 1) {
        for (int s = cur + 1; s <= N; ++s) offs[s] = E;
    }
}

__global__ __launch_bounds__(256) void seg_mean_kernel(
    const float* __restrict__ values,
    const int*   __restrict__ offs,
    float*       __restrict__ out,
    int N)
{
    const int wave = threadIdx.x >> 6;               // 0..3
    const int s    = blockIdx.x * 4 + wave;
    if (s >= N) return;

    const int start = offs[s];
    const int end   = offs[s + 1];
    const int count = end - start;

    const int t    = threadIdx.x & 63;
    const int rsub = t >> 4;          // row-in-group-of-4: 0..3
    const int c4   = (t & 15) << 2;   // column base: 0,4,...,60

    float4 acc = make_float4(0.f, 0.f, 0.f, 0.f);
    for (int r = start + rsub; r < end; r += 4) {
        const float4 v = *reinterpret_cast<const float4*>(values + (size_t)r * 64 + c4);
        acc.x += v.x; acc.y += v.y; acc.z += v.z; acc.w += v.w;
    }

    // fold the 4 row-subgroups (lanes differing in bits 4,5 share columns)
    acc.x += __shfl_xor(acc.x, 16, 64);
    acc.y += __shfl_xor(acc.y, 16, 64);
    acc.z += __shfl_xor(acc.z, 16, 64);
    acc.w += __shfl_xor(acc.w, 16, 64);
    acc.x += __shfl_xor(acc.x, 32, 64);
    acc.y += __shfl_xor(acc.y, 32, 64);
    acc.z += __shfl_xor(acc.z, 32, 64);
    acc.w += __shfl_xor(acc.w, 32, 64);

    if (t < 16) {
        const float inv = (count > 0) ? (1.0f / (float)count) : 0.0f;
        float4 o;
        o.x = acc.x * inv; o.y = acc.y * inv; o.z = acc.z * inv; o.w = acc.w * inv;
        *reinterpret_cast<float4*>(out + (size_t)s * 64 + c4) = o;
    }
}

extern "C" void kernel_launch(void* const* d_in, const int* in_sizes, int n_in,
                              void* d_out, int out_size, void* d_ws, size_t ws_size,
                              hipStream_t stream) {
    const float* values  = (const float*)d_in[0];
    const int*   seg_ids = (const int*)d_in[1];
    float*       out     = (float*)d_out;
    int*         offs    = (int*)d_ws;   // (N+1) ints

    const int E = in_sizes[1];        // number of rows (= len(segment_ids))
    const int N = out_size / 64;      // number of segments (D = 64)

    seg_bounds_kernel<<<dim3((E + 255) / 256), dim3(256), 0, stream>>>(seg_ids, offs, E, N);
    seg_mean_kernel<<<dim3((N + 3) / 4), dim3(256), 0, stream>>>(values, offs, out, N);
}

// Round 3
// 67.635 us; speedup vs baseline: 1.4234x; 1.0497x over previous
//
#include <hip/hip_runtime.h>

// Segmented mean over sorted segment ids, two-kernel plan:
//   K1 (boundary pre-pass, int4-vectorized): offs[s] = lower_bound(seg_ids, s)
//       for s in [0, N], computed in O(E) with no searches (ids are sorted).
//   K2 (stream): one wave per segment; lane t accumulates float4 at
//       offset start*64 + 4*t (row start+(t>>4), col (t&15)*4), striding
//       4 rows; unrolled by 2 (2 loads in flight); shfl_xor fold; lanes
//       0..15 store one float4 each. 4 segments (4 waves) per 256-thread block.

__global__ __launch_bounds__(256) void seg_bounds_kernel(
    const int* __restrict__ seg_ids,
    int*       __restrict__ offs,   // [N+1]
    int E, int N)
{
    const int q    = blockIdx.x * blockDim.x + threadIdx.x;  // quad index
    const int base = q << 2;
    if (base >= E) return;

    int id0, id1, id2, id3;
    int nv = E - base;                       // >=1
    if (nv >= 4) {
        const int4 v = *reinterpret_cast<const int4*>(seg_ids + base);
        id0 = v.x; id1 = v.y; id2 = v.z; id3 = v.w;
    } else {
        id0 = seg_ids[base];
        id1 = (nv > 1) ? seg_ids[base + 1] : id0;
        id2 = (nv > 2) ? seg_ids[base + 2] : id1;
        id3 = id2;
    }

    int prev = (base > 0) ? seg_ids[base - 1] : -1;

    // first row of every segment in (prev, id_j] is base+j
    for (int s = prev + 1; s <= id0; ++s) offs[s] = base + 0;
    if (nv > 1) for (int s = id0 + 1; s <= id1; ++s) offs[s] = base + 1;
    if (nv > 2) for (int s = id1 + 1; s <= id2; ++s) offs[s] = base + 2;
    if (nv > 3) for (int s = id2 + 1; s <= id3; ++s) offs[s] = base + 3;

    if (base + 4 >= E) {                     // last quad fills the tail
        for (int s = id3 + 1; s <= N; ++s) offs[s] = E;
    }
}

__global__ __launch_bounds__(256) void seg_mean_kernel(
    const float* __restrict__ values,
    const int*   __restrict__ offs,
    float*       __restrict__ out,
    int N)
{
    const int wave = threadIdx.x >> 6;               // 0..3
    const int s    = blockIdx.x * 4 + wave;
    if (s >= N) return;

    const int t = threadIdx.x & 63;

    const int start = offs[s];
    const int end   = offs[s + 1];
    const int count = end - start;

    // lane t covers row start+(t>>4)+4k, cols (t&15)*4 .. +3
    // flat float offset: start*64 + 4*t, stride 256 floats per 4-row step
    const float* p = values + (size_t)start * 64 + (t << 2);
    const int rsub = t >> 4;

    float4 a0 = make_float4(0.f, 0.f, 0.f, 0.f);
    float4 a1 = make_float4(0.f, 0.f, 0.f, 0.f);

    int r = start + rsub;
    // unrolled by 2: rows r and r+4 both valid while r+4 < end
    for (; r + 4 < end; r += 8, p += 512) {
        const float4 v0 = *reinterpret_cast<const float4*>(p);
        const float4 v1 = *reinterpret_cast<const float4*>(p + 256);
        a0.x += v0.x; a0.y += v0.y; a0.z += v0.z; a0.w += v0.w;
        a1.x += v1.x; a1.y += v1.y; a1.z += v1.z; a1.w += v1.w;
    }
    if (r < end) {
        const float4 v0 = *reinterpret_cast<const float4*>(p);
        a0.x += v0.x; a0.y += v0.y; a0.z += v0.z; a0.w += v0.w;
    }

    float4 acc;
    acc.x = a0.x + a1.x; acc.y = a0.y + a1.y;
    acc.z = a0.z + a1.z; acc.w = a0.w + a1.w;

    // fold the 4 row-subgroups (lanes differing in bits 4,5 share columns)
    acc.x += __shfl_xor(acc.x, 16, 64);
    acc.y += __shfl_xor(acc.y, 16, 64);
    acc.z += __shfl_xor(acc.z, 16, 64);
    acc.w += __shfl_xor(acc.w, 16, 64);
    acc.x += __shfl_xor(acc.x, 32, 64);
    acc.y += __shfl_xor(acc.y, 32, 64);
    acc.z += __shfl_xor(acc.z, 32, 64);
    acc.w += __shfl_xor(acc.w, 32, 64);

    if (t < 16) {
        const float inv = (count > 0) ? (1.0f / (float)count) : 0.0f;
        float4 o;
        o.x = acc.x * inv; o.y = acc.y * inv; o.z = acc.z * inv; o.w = acc.w * inv;
        *reinterpret_cast<float4*>(out + (size_t)s * 64 + ((t & 15) << 2)) = o;
    }
}

extern "C" void kernel_launch(void* const* d_in, const int* in_sizes, int n_in,
                              void* d_out, int out_size, void* d_ws, size_t ws_size,
                              hipStream_t stream) {
    const float* values  = (const float*)d_in[0];
    const int*   seg_ids = (const int*)d_in[1];
    float*       out     = (float*)d_out;
    int*         offs    = (int*)d_ws;   // (N+1) ints

    const int E = in_sizes[1];        // number of rows (= len(segment_ids))
    const int N = out_size / 64;      // number of segments (D = 64)

    const int quads = (E + 3) / 4;
    seg_bounds_kernel<<<dim3((quads + 255) / 256), dim3(256), 0, stream>>>(seg_ids, offs, E, N);
    seg_mean_kernel<<<dim3((N + 3) / 4), dim3(256), 0, stream>>>(values, offs, out, N);
}